// Round 2
// baseline (308.937 us; speedup 1.0000x reference)
//
#include <hip/hip_runtime.h>

#define BT_D   512
#define BT_D4  128   // float4 groups per row
#define NBLK   1024  // 4 blocks/CU
#define NTHR   256   // 4 waves/block
#define NWAVE  4
#define DEPTH  4     // wave-private pipeline stages; 8 gload_lds in flight/wave

// Accumulate one (e,tau) float4 pair into the 5 stat accumulators.
#define BT_ACC(ev, tv)                                                  \
    do {                                                                \
        se.x += (ev).x; se.y += (ev).y; se.z += (ev).z; se.w += (ev).w; \
        st.x += (tv).x; st.y += (tv).y; st.z += (tv).z; st.w += (tv).w; \
        se2.x = fmaf((ev).x, (ev).x, se2.x);                            \
        se2.y = fmaf((ev).y, (ev).y, se2.y);                            \
        se2.z = fmaf((ev).z, (ev).z, se2.z);                            \
        se2.w = fmaf((ev).w, (ev).w, se2.w);                            \
        st2.x = fmaf((tv).x, (tv).x, st2.x);                            \
        st2.y = fmaf((tv).y, (tv).y, st2.y);                            \
        st2.z = fmaf((tv).z, (tv).z, st2.z);                            \
        st2.w = fmaf((tv).w, (tv).w, st2.w);                            \
        set.x = fmaf((ev).x, (tv).x, set.x);                            \
        set.y = fmaf((ev).y, (tv).y, set.y);                            \
        set.z = fmaf((ev).z, (tv).z, set.z);                            \
        set.w = fmaf((ev).w, (tv).w, set.w);                            \
    } while (0)

#define BT_ADD4(dst, a) \
    do { (dst).x += (a).x; (dst).y += (a).y; (dst).z += (a).z; (dst).w += (a).w; } while (0)

// Issue one pipeline stage: 1 KB of e + 1 KB of t into wave-private LDS slot.
// Global src is per-lane (base + lane*16); LDS dest is wave-uniform base and
// HW writes lane*16 — lane order matches (m104 semantics).
#define BT_ISSUE(sidx, slot_)                                                     \
    do {                                                                          \
        unsigned _p = p0 + (sidx);                                                \
        if (_p >= pend) _p = pend - 1; /* dummy re-issue keeps vmcnt uniform */   \
        const unsigned _c = (_p << 1) | par;                                      \
        const size_t _o = ((size_t)_c << 6) + (unsigned)lane;                     \
        __builtin_amdgcn_global_load_lds(                                         \
            (const __attribute__((address_space(1))) void*)(e4 + _o),            \
            (__attribute__((address_space(3))) void*)&buf_e[w][slot_][0],        \
            16, 0, 0);                                                            \
        __builtin_amdgcn_global_load_lds(                                         \
            (const __attribute__((address_space(1))) void*)(t4 + _o),            \
            (__attribute__((address_space(3))) void*)&buf_t[w][slot_][0],        \
            16, 0, 0);                                                            \
    } while (0)

// Kernel 1: async global->LDS streaming reduce.
// R1 post-mortem: regalloc sinks VGPR loads to uses at ANY launch_bounds
// (36/24 VGPR, 1 load in flight, 2.5 TB/s). Fix: global_load_lds pipeline —
// in-flight bytes live in LDS, waits are explicit counted vmcnt (T3/T4).
// Chunk = 64 float4 = half a row, so wave takes one PARITY class only:
// lane l of wave w always owns column group l + 64*(wg&1).
__global__ __launch_bounds__(NTHR, 4) void bt_partial_kernel(
    const float4* __restrict__ e4, const float4* __restrict__ t4,
    float* __restrict__ acc, int B, int nslot)
{
    const int tid  = threadIdx.x;
    const int w    = tid >> 6;
    const int lane = tid & 63;

    __shared__ float4 buf_e[NWAVE][DEPTH][64];   // 16 KB
    __shared__ float4 buf_t[NWAVE][DEPTH][64];   // 16 KB

    float4 se  = make_float4(0.f, 0.f, 0.f, 0.f);
    float4 se2 = make_float4(0.f, 0.f, 0.f, 0.f);
    float4 st  = make_float4(0.f, 0.f, 0.f, 0.f);
    float4 st2 = make_float4(0.f, 0.f, 0.f, 0.f);
    float4 set = make_float4(0.f, 0.f, 0.f, 0.f);

    // 1 KB chunks per array: nchunk = B*128/64 = 2B, split by parity.
    const unsigned npair  = (unsigned)B;                 // chunks per parity
    const unsigned wg     = (unsigned)blockIdx.x * NWAVE + w;
    const unsigned par    = wg & 1u;
    const unsigned pairid = wg >> 1;
    const unsigned PW     = (NBLK * NWAVE) >> 1;         // 2048 parity streams
    const unsigned cpw    = (npair + PW - 1) / PW;       // 32 for B=65536
    const unsigned p0     = pairid * cpw;
    const unsigned pend   = (p0 + cpw < npair) ? (p0 + cpw) : npair;

    if (p0 < pend) {
        const unsigned steps = pend - p0;
        BT_ISSUE(0u, 0); BT_ISSUE(1u, 1); BT_ISSUE(2u, 2); BT_ISSUE(3u, 3);
        for (unsigned s = 0; s < steps; ++s) {
            const unsigned slot = s & (DEPTH - 1);
            // 8 loads outstanding; wait until the oldest stage's pair lands.
            asm volatile("s_waitcnt vmcnt(6)" ::: "memory");
            const float4 ev = buf_e[w][slot][lane];
            const float4 tv = buf_t[w][slot][lane];
            asm volatile("" ::: "memory");   // pin re-issue below the reads
            BT_ISSUE(s + DEPTH, slot);
            BT_ACC(ev, tv);
        }
    }
    // Drain all (incl. dummy) gload_lds before LDS is reused as scratch.
    asm volatile("s_waitcnt vmcnt(0)" ::: "memory");
    __syncthreads();

    // Fold waves 2,3 into 0,1 (same parity pairs: w0<-w2, w1<-w3), then
    // threads 0..127 hold all 128 column groups: col4 = lane + 64*w.
    float4 (*scr)[5] = (float4 (*)[5])&buf_e[0][0][0];   // 10 KB scratch
    if (w >= 2) {
        float4 (*L)[5] = scr + (w - 2) * 64;
        L[lane][0] = se;  L[lane][1] = se2; L[lane][2] = st;
        L[lane][3] = st2; L[lane][4] = set;
    }
    __syncthreads();
    if (w < 2) {
        float4 (*L)[5] = scr + w * 64;
        BT_ADD4(se,  L[lane][0]); BT_ADD4(se2, L[lane][1]);
        BT_ADD4(st,  L[lane][2]); BT_ADD4(st2, L[lane][3]);
        BT_ADD4(set, L[lane][4]);

        float* ap = acc + (size_t)(blockIdx.x & (nslot - 1)) * (5 * BT_D);
        const int col = (lane + (w << 6)) * 4;
        atomicAdd(&ap[0 * BT_D + col + 0], se.x);
        atomicAdd(&ap[0 * BT_D + col + 1], se.y);
        atomicAdd(&ap[0 * BT_D + col + 2], se.z);
        atomicAdd(&ap[0 * BT_D + col + 3], se.w);
        atomicAdd(&ap[1 * BT_D + col + 0], se2.x);
        atomicAdd(&ap[1 * BT_D + col + 1], se2.y);
        atomicAdd(&ap[1 * BT_D + col + 2], se2.z);
        atomicAdd(&ap[1 * BT_D + col + 3], se2.w);
        atomicAdd(&ap[2 * BT_D + col + 0], st.x);
        atomicAdd(&ap[2 * BT_D + col + 1], st.y);
        atomicAdd(&ap[2 * BT_D + col + 2], st.z);
        atomicAdd(&ap[2 * BT_D + col + 3], st.w);
        atomicAdd(&ap[3 * BT_D + col + 0], st2.x);
        atomicAdd(&ap[3 * BT_D + col + 1], st2.y);
        atomicAdd(&ap[3 * BT_D + col + 2], st2.z);
        atomicAdd(&ap[3 * BT_D + col + 3], st2.w);
        atomicAdd(&ap[4 * BT_D + col + 0], set.x);
        atomicAdd(&ap[4 * BT_D + col + 1], set.y);
        atomicAdd(&ap[4 * BT_D + col + 2], set.z);
        atomicAdd(&ap[4 * BT_D + col + 3], set.w);
    }
}

#define BT_FIN(Se_, Se2_, St_, St2_, Set_)                               \
    do {                                                                 \
        const double Se = (Se_), Se2 = (Se2_), St = (St_), St2 = (St2_), \
                     Set = (Set_);                                       \
        const double me = Se / Bd, mt = St / Bd;                         \
        double ve = (Se2 - Bd * me * me) / (Bd - 1.0);                   \
        double vt = (St2 - Bd * mt * mt) / (Bd - 1.0);                   \
        ve = ve > 0.0 ? ve : 0.0;                                        \
        vt = vt > 0.0 ? vt : 0.0;                                        \
        const double sd_e = sqrt(ve) + 1e-9;                             \
        const double sd_t = sqrt(vt) + 1e-9;                             \
        const double c = (Set - Bd * me * mt) / (sd_e * sd_t * Bd);      \
        vsum += (1.0 - c) * (1.0 - c);                                   \
    } while (0)

// Kernel 2: finalize. Single block (no d_out memset needed), float4 loads,
// 4-way slot-phase parallel then LDS fold, fp64 math, tree reduce.
__global__ __launch_bounds__(512) void bt_final_kernel(
    const float* __restrict__ acc, float* __restrict__ out, int B, int nslot)
{
    const int t  = threadIdx.x;
    const int c4 = t & 127;
    const int q  = t >> 7;   // slot phase 0..3

    float4 S0 = make_float4(0.f, 0.f, 0.f, 0.f);
    float4 S1 = S0, S2 = S0, S3 = S0, S4 = S0;
    const float4* a4 = (const float4*)acc;
    for (int s = q; s < nslot; s += 4) {
        const float4* a = a4 + (size_t)s * (5 * BT_D4);
        float4 x;
        x = a[0 * BT_D4 + c4]; BT_ADD4(S0, x);
        x = a[1 * BT_D4 + c4]; BT_ADD4(S1, x);
        x = a[2 * BT_D4 + c4]; BT_ADD4(S2, x);
        x = a[3 * BT_D4 + c4]; BT_ADD4(S3, x);
        x = a[4 * BT_D4 + c4]; BT_ADD4(S4, x);
    }

    __shared__ float4 L[3][128][5];   // 30 KB
    __shared__ double R[128];
    if (q) {
        L[q - 1][c4][0] = S0; L[q - 1][c4][1] = S1; L[q - 1][c4][2] = S2;
        L[q - 1][c4][3] = S3; L[q - 1][c4][4] = S4;
    }
    __syncthreads();
    if (q == 0) {
        for (int j = 0; j < 3; ++j) {
            BT_ADD4(S0, L[j][c4][0]); BT_ADD4(S1, L[j][c4][1]);
            BT_ADD4(S2, L[j][c4][2]); BT_ADD4(S3, L[j][c4][3]);
            BT_ADD4(S4, L[j][c4][4]);
        }
        const double Bd = (double)B;
        double vsum = 0.0;
        BT_FIN(S0.x, S1.x, S2.x, S3.x, S4.x);
        BT_FIN(S0.y, S1.y, S2.y, S3.y, S4.y);
        BT_FIN(S0.z, S1.z, S2.z, S3.z, S4.z);
        BT_FIN(S0.w, S1.w, S2.w, S3.w, S4.w);
        R[c4] = vsum;
    }
    __syncthreads();
    for (int s2 = 64; s2 > 0; s2 >>= 1) {
        if (t < s2) R[t] += R[t + s2];
        __syncthreads();
    }
    if (t == 0) out[0] = (float)R[0];
}

extern "C" void kernel_launch(void* const* d_in, const int* in_sizes, int n_in,
                              void* d_out, int out_size, void* d_ws, size_t ws_size,
                              hipStream_t stream) {
    const float* e   = (const float*)d_in[0];
    const float* tau = (const float*)d_in[1];
    const int B = in_sizes[0] / BT_D;
    float* acc = (float*)d_ws;

    // accumulator copies: atomic same-address chain depth = NBLK / nslot
    int nslot = 1;
    const size_t slot_bytes = (size_t)5 * BT_D * sizeof(float);
    if (ws_size >= 32 * slot_bytes)      nslot = 32;
    else if (ws_size >= 8 * slot_bytes)  nslot = 8;
    else if (ws_size >= 4 * slot_bytes)  nslot = 4;
    else if (ws_size >= 2 * slot_bytes)  nslot = 2;

    (void)hipMemsetAsync(d_ws, 0, (size_t)nslot * slot_bytes, stream);

    bt_partial_kernel<<<NBLK, NTHR, 0, stream>>>(
        (const float4*)e, (const float4*)tau, acc, B, nslot);
    bt_final_kernel<<<1, 512, 0, stream>>>(acc, (float*)d_out, B, nslot);
}